// Round 5
// baseline (107.724 us; speedup 1.0000x reference)
//
#include <hip/hip_runtime.h>
#include <math.h>

// LightconvLayer: x (T,B,C) f32, weight (H,K) f32 -> out (T,B,C) f32
// out[t,b,c] = sum_k softmax(weight[c/(C/H)])[k] * x[t+k-PAD_L, b, c] (zero-pad left)
#define T_LEN 2048
#define B_SZ  8
#define C_SZ  1024
#define NH    16
#define KW    31
#define PADL  30
#define TT    8       // output rows per block along t (small -> low VGPR -> high occupancy)
#define BLOCK 256     // 256 threads x float4 = all 1024 channels
#define NSTRIP (T_LEN / TT)   // 256 t-strips, %8 == 0 -> bijective XCD swizzle

template <bool CLIP>
__device__ __forceinline__ void conv_body(const float4* __restrict__ xp,
                                          float4* __restrict__ op,
                                          const float* __restrict__ wk,
                                          int t0) {
  const int R4 = B_SZ * C_SZ / 4;  // float4 stride between t rows = 2048

  float4 acc[TT];
#pragma unroll
  for (int o = 0; o < TT; ++o) acc[o] = make_float4(0.f, 0.f, 0.f, 0.f);

  // stream input rows i = 0..TT+KW-2  (t = t0 + i - PADL); all indices
  // compile-time constants -> acc/wk stay in registers (rule #20).
#pragma unroll
  for (int i = 0; i < TT + KW - 1; ++i) {
    const int t = t0 + i - PADL;
    float4 xv;
    if (CLIP) {
      xv = (t >= 0) ? xp[(size_t)t * R4] : make_float4(0.f, 0.f, 0.f, 0.f);
    } else {
      xv = xp[(size_t)t * R4];
    }
#pragma unroll
    for (int o = 0; o < TT; ++o) {
      const int k = i - o;               // compile-time constant
      if (k >= 0 && k < KW) {            // constant-folds away
        const float w = wk[k];
        acc[o].x = fmaf(w, xv.x, acc[o].x);
        acc[o].y = fmaf(w, xv.y, acc[o].y);
        acc[o].z = fmaf(w, xv.z, acc[o].z);
        acc[o].w = fmaf(w, xv.w, acc[o].w);
      }
    }
  }

#pragma unroll
  for (int o = 0; o < TT; ++o) {
    op[(size_t)o * R4] = acc[o];
  }
}

// (256, 3): min 12 waves/CU -> VGPR cap ~170. Kernel needs ~90; prevents the
// R3 pathology (allocator squeezing to 64 VGPR and spilling acc to scratch).
__global__ __launch_bounds__(BLOCK, 3) void lightconv_kernel(
    const float* __restrict__ x, const float* __restrict__ weight,
    float* __restrict__ out) {
  __shared__ float sw[NH][KW];
  const int tid = threadIdx.x;

  // --- softmax(weight) into LDS: 16 threads, one head each ---
  if (tid < NH) {
    float wv[KW];
    float m = -1e30f;
#pragma unroll
    for (int k = 0; k < KW; ++k) {
      wv[k] = weight[tid * KW + k];
      m = fmaxf(m, wv[k]);
    }
    float s = 0.f;
#pragma unroll
    for (int k = 0; k < KW; ++k) {
      wv[k] = expf(wv[k] - m);
      s += wv[k];
    }
    const float inv = 1.f / s;
#pragma unroll
    for (int k = 0; k < KW; ++k) sw[tid][k] = wv[k] * inv;
  }
  __syncthreads();

  // thread -> 4 consecutive channels (float4); head = (4*tid)/64 = tid>>4
  const int head = tid >> 4;
  float wk[KW];
#pragma unroll
  for (int k = 0; k < KW; ++k) wk[k] = sw[head][k];

  // XCD-aware strip swizzle (T1): consecutive t-strips (which share a 30-row
  // halo) land on the SAME XCD's L2. gridDim.x = 256 (%8==0 -> bijective);
  // linear-id % 8 == blockIdx.x % 8 since gridDim.x % 8 == 0.
  const int strip = (blockIdx.x % 8) * (NSTRIP / 8) + blockIdx.x / 8;
  const int b  = blockIdx.y;
  const int t0 = strip * TT;

  const float4* xp = (const float4*)x + (size_t)b * (C_SZ / 4) + tid;
  float4* op = (float4*)out + ((size_t)t0 * B_SZ + b) * (C_SZ / 4) + tid;

  // Only strips with t0 < PADL can see t < 0.
  if (t0 >= PADL) {
    conv_body<false>(xp, op, wk, t0);
  } else {
    conv_body<true>(xp, op, wk, t0);
  }
}

extern "C" void kernel_launch(void* const* d_in, const int* in_sizes, int n_in,
                              void* d_out, int out_size, void* d_ws, size_t ws_size,
                              hipStream_t stream) {
  const float* x = (const float*)d_in[0];      // (T,B,C) f32
  const float* w = (const float*)d_in[1];      // (H,K) f32
  float* out = (float*)d_out;                  // (T,B,C) f32
  (void)in_sizes; (void)n_in; (void)out_size; (void)d_ws; (void)ws_size;

  dim3 grid(NSTRIP, B_SZ);                     // (256, 8) = 2048 blocks
  dim3 block(BLOCK);
  lightconv_kernel<<<grid, block, 0, stream>>>(x, w, out);
}

// Round 6
// 35.590 us; speedup vs baseline: 3.0268x; 3.0268x over previous
//
#include <hip/hip_runtime.h>
#include <math.h>
#include <stdint.h>

// LightconvLayer: x (T,B,C) f32, weight (H,K) f32 -> out (T,B,C) f32
// out[t,b,c] = sum_k softmax(weight[c/64])[k] * x[t+k-30, b, c] (zero-pad left)
//
// Structure (R6): global_load_lds ring pipeline.
//  - block = 256 thr (4 waves) owns (batch b, 256-channel group, 128-row t-chunk)
//  - LDS ring: 64 rows x 256 ch x f32 = 64 KB -> 2 blocks/CU
//  - per 16-row tile: stage next tile via 4x global_load_lds(16B) per wave
//    (zero VGPR cost), counted s_waitcnt vmcnt(4) (T4 - never drain),
//    raw s_barrier, compute from LDS (46 ds_read_b32 + 496 FMA, taps in SGPR
//    since each wave = one head), 16 dword stores, raw s_barrier.
//  - ring aliasing: compute-j reads slots (t0-30..t0+15)%64 (46), stage-j+1
//    writes (t0+16..t0+31)%64 (16) -> disjoint (62<=64). stage-j+2 clobbers
//    compute-j slots but is fenced by the end-of-iter barrier.
#define T_LEN 2048
#define B_SZ  8
#define C_SZ  1024
#define NH    16
#define KW    31
#define HALO  (KW - 1)        // 30
#define BLOCK 256
#define CG    256             // channels per block
#define TT    16              // rows per tile
#define CHUNK 128             // rows per block
#define NTILE (CHUNK / TT)    // 8
#define RING  64              // ring rows (pow2, >= 46+16)
#define WIN   (TT + HALO)     // 46
#define ROWSTRIDE (B_SZ * C_SZ)  // 8192 floats between t rows

#define GLOBAL_AS(p) ((const __attribute__((address_space(1))) void*)(p))
#define LDS_AS(p)    ((__attribute__((address_space(3))) void*)(p))

__global__ __launch_bounds__(BLOCK, 2) void lightconv_kernel(
    const float* __restrict__ x, const float* __restrict__ weight,
    float* __restrict__ out) {
  __shared__ float ring[RING][CG];
  __shared__ float sw[NH][KW];

  const int tid  = threadIdx.x;
  const int wave = tid >> 6;
  const int lane = tid & 63;

  const int cg = blockIdx.x & 3;    // channel group 0..3
  const int tc = blockIdx.x >> 2;   // t-chunk 0..15
  const int b  = blockIdx.y;
  const int c0 = cg * CG;
  const int tb = tc * CHUNK;

  // --- softmax(weight) into LDS: 16 threads, one head each ---
  if (tid < NH) {
    float wv[KW];
    float m = -1e30f;
#pragma unroll
    for (int k = 0; k < KW; ++k) {
      wv[k] = weight[tid * KW + k];
      m = fmaxf(m, wv[k]);
    }
    float s = 0.f;
#pragma unroll
    for (int k = 0; k < KW; ++k) {
      wv[k] = expf(wv[k] - m);
      s += wv[k];
    }
    const float inv = 1.f / s;
#pragma unroll
    for (int k = 0; k < KW; ++k) sw[tid][k] = wv[k] * inv;
  }

  // --- prologue: stage rows tb-30 .. tb+15 (46 rows) into the ring ---
  // wave-uniform per-row work; lane provides the per-lane global address
  // (16B per lane); LDS dest is wave-uniform base + lane*16 (linear row).
  const float* xbase = x + (size_t)b * C_SZ + c0;  // + t*ROWSTRIDE
#pragma unroll
  for (int rr = 0; rr < 12; ++rr) {
    const int idx = wave + rr * 4;       // wave-uniform
    if (idx < WIN) {
      const int t = tb - HALO + idx;
      if (t >= 0) {                       // wave-uniform (t depends on idx only)
        const int slot = (t + 2048) & (RING - 1);
        const float* gp = xbase + (size_t)t * ROWSTRIDE + lane * 4;
        __builtin_amdgcn_global_load_lds(GLOBAL_AS(gp), LDS_AS(&ring[slot][0]),
                                         16, 0, 0);
      }
    }
  }
  // zero-fill t<0 rows (only chunk 0)
  if (tb == 0) {
#pragma unroll
    for (int i = 0; i < HALO; ++i) {
      ring[(i - HALO + 2048) & (RING - 1)][tid] = 0.f;  // rows -30..-1
    }
  }
  __syncthreads();  // drains prologue vmcnt + makes sw visible

  // taps -> SGPR: wave covers channels [c0+64*wave, +64) = exactly one head
  const int head = (c0 >> 6) + wave;     // wave-uniform
  float wk[KW];
#pragma unroll
  for (int k = 0; k < KW; ++k) {
    wk[k] = __uint_as_float(
        __builtin_amdgcn_readfirstlane(__float_as_uint(sw[head][k])));
  }

  // --- main loop over 8 tiles of 16 rows ---
  for (int j = 0; j < NTILE; ++j) {
    const int tstart = tb + j * TT;

    if (j + 1 < NTILE) {
      // A: stage tile j+1 (rows tstart+16 .. tstart+31), 4 rows per wave
#pragma unroll
      for (int rr = 0; rr < TT / 4; ++rr) {
        const int t = tstart + TT + wave + rr * 4;
        const int slot = t & (RING - 1);
        const float* gp = xbase + (size_t)t * ROWSTRIDE + lane * 4;
        __builtin_amdgcn_global_load_lds(GLOBAL_AS(gp), LDS_AS(&ring[slot][0]),
                                         16, 0, 0);
      }
      // B: counted wait - tile j's 4 loads (older) done, j+1's 4 stay in flight
      asm volatile("s_waitcnt vmcnt(4)" ::: "memory");
    } else {
      asm volatile("s_waitcnt vmcnt(0)" ::: "memory");
    }
    __builtin_amdgcn_s_barrier();         // all waves' tile-j rows are in LDS
    __builtin_amdgcn_sched_barrier(0);    // rule #18: pin ds_reads below

    // C: compute tile j from the ring (thread = channel c0+tid)
    float xv[WIN];
#pragma unroll
    for (int i = 0; i < WIN; ++i) {
      const int t = tstart - HALO + i;
      xv[i] = ring[(t + 2048) & (RING - 1)][tid];
    }
    float* op = out + ((size_t)tstart * B_SZ + b) * C_SZ + c0 + tid;
#pragma unroll
    for (int o = 0; o < TT; ++o) {
      float a = 0.f;
#pragma unroll
      for (int k = 0; k < KW; ++k) a = fmaf(wk[k], xv[o + k], a);
      op[(size_t)o * ROWSTRIDE] = a;
    }

    // D: fence - next iter's stage (tile j+2) clobbers slots read by tile j
    __builtin_amdgcn_s_barrier();
    __builtin_amdgcn_sched_barrier(0);
  }
}

extern "C" void kernel_launch(void* const* d_in, const int* in_sizes, int n_in,
                              void* d_out, int out_size, void* d_ws, size_t ws_size,
                              hipStream_t stream) {
  const float* x = (const float*)d_in[0];      // (T,B,C) f32
  const float* w = (const float*)d_in[1];      // (H,K) f32
  float* out = (float*)d_out;                  // (T,B,C) f32
  (void)in_sizes; (void)n_in; (void)out_size; (void)d_ws; (void)ws_size;

  dim3 grid((T_LEN / CHUNK) * (C_SZ / CG), B_SZ);  // (64, 8) = 512 blocks, 2/CU
  dim3 block(BLOCK);
  lightconv_kernel<<<grid, block, 0, stream>>>(x, w, out);
}

// Round 7
// 33.483 us; speedup vs baseline: 3.2173x; 1.0629x over previous
//
#include <hip/hip_runtime.h>
#include <math.h>

// LightconvLayer: x (T,B,C) f32, weight (H,K) f32 -> out (T,B,C) f32
// out[t,b,c] = sum_k softmax(weight[c/64])[k] * x[t+k-30, b, c] (zero-pad left)
//
// R7: WAVE-AUTONOMOUS pipeline - no s_barrier at all.
//  - 1 wave (64 thr) owns (batch b, head = 64 channels, 128-row t-chunk)
//  - wave-private LDS ring: 64 slots x 64 ch x f32 = 16 KB
//  - per 16-row tile: stage next tile = 16x global_load_lds(width 4, 256 B
//    row slices, zero VGPR), counted s_waitcnt vmcnt(31) (drains tile-j's
//    16 loads + <=1 old store; never waits on young stores), compute
//    46 ds_read_b32 (2-way bank = free) + 496 FMA with SGPR taps, 16 stores.
//  - taps: uniform s_loads + uniform softmax + readfirstlane -> SGPRs.
#define T_LEN 2048
#define B_SZ  8
#define C_SZ  1024
#define NH    16
#define KW    31
#define HALO  (KW - 1)        // 30
#define TT    16              // rows per tile
#define CHUNK 128             // rows per wave
#define NTILE (CHUNK / TT)    // 8
#define RING  64              // ring slots (pow2 >= 46+16)
#define WIN   (TT + HALO)     // 46
#define ROWSTRIDE (B_SZ * C_SZ)  // 8192 floats between t rows

#define GLOBAL_AS(p) ((const __attribute__((address_space(1))) void*)(p))
#define LDS_AS(p)    ((__attribute__((address_space(3))) void*)(p))

__global__ __launch_bounds__(64, 2) void lightconv_kernel(
    const float* __restrict__ x, const float* __restrict__ weight,
    float* __restrict__ out) {
  __shared__ float ring[RING][64];   // 16 KB, wave-private (1 wave/block)
  const int lane = threadIdx.x;      // 0..63 = channel within head

  const int cgrp = blockIdx.x & 15;  // head / channel group (C/64 = 16 = NH)
  const int tc   = blockIdx.x >> 4;  // t-chunk 0..15
  const int b    = blockIdx.y;
  const int c0   = cgrp * 64;
  const int tb   = tc * CHUNK;

  // --- taps: uniform scalar loads -> uniform softmax -> SGPR via readfirstlane
  float wv[KW];
  float m = -1e30f;
#pragma unroll
  for (int k = 0; k < KW; ++k) {
    wv[k] = weight[cgrp * KW + k];   // uniform address -> s_load
    m = fmaxf(m, wv[k]);
  }
  float s = 0.f;
#pragma unroll
  for (int k = 0; k < KW; ++k) {
    wv[k] = expf(wv[k] - m);
    s += wv[k];
  }
  const float inv = 1.f / s;
  float wk[KW];
#pragma unroll
  for (int k = 0; k < KW; ++k) {
    wk[k] = __uint_as_float(
        __builtin_amdgcn_readfirstlane(__float_as_uint(wv[k] * inv)));
  }

  const float* xbase = x + (size_t)b * C_SZ + c0;  // + t*ROWSTRIDE + lane*4B

  // --- prologue: stage window of tile 0 (rows tb-30 .. tb+15) ---
  if (tb == 0) {
#pragma unroll
    for (int i = 0; i < HALO; ++i) {         // rows -30..-1 -> zero
      ring[(2048 - HALO + i) & (RING - 1)][lane] = 0.f;
    }
#pragma unroll
    for (int i = 0; i < TT; ++i) {           // rows 0..15
      const float* gp = xbase + (size_t)i * ROWSTRIDE + lane;
      __builtin_amdgcn_global_load_lds(GLOBAL_AS(gp),
                                       LDS_AS(&ring[i & (RING - 1)][0]), 4, 0, 0);
    }
  } else {
#pragma unroll
    for (int i = 0; i < WIN; ++i) {          // rows tb-30 .. tb+15
      const int t = tb - HALO + i;
      const float* gp = xbase + (size_t)t * ROWSTRIDE + lane;
      __builtin_amdgcn_global_load_lds(GLOBAL_AS(gp),
                                       LDS_AS(&ring[(t + 2048) & (RING - 1)][0]),
                                       4, 0, 0);
    }
  }

  // --- main loop: 8 tiles, no barriers, counted vmcnt only ---
#pragma unroll 1
  for (int j = 0; j < NTILE; ++j) {
    const int tstart = tb + j * TT;

    if (j + 1 < NTILE) {
      // stage tile j+1 (rows tstart+16 .. tstart+31); ring slack: 46+16=62<=64
#pragma unroll
      for (int r = 0; r < TT; ++r) {
        const int t = tstart + TT + r;
        const float* gp = xbase + (size_t)t * ROWSTRIDE + lane;
        __builtin_amdgcn_global_load_lds(GLOBAL_AS(gp),
                                         LDS_AS(&ring[(t + 2048) & (RING - 1)][0]),
                                         4, 0, 0);
      }
    }
    // counted wait: guarantee tile-j's 16 loads retired.
    //  mid-loop outstanding (old->new): loads-j(16), stores-(j-1)(16),
    //  loads-(j+1)(16) -> vmcnt(31) drains loads-j + at most 1 store.
    //  j==0: prologue(<=46)+loads-1(16) -> need vmcnt(16).
    //  j==NTILE-1: loads-j(16)+stores-(j-1)(16), no new loads -> vmcnt(16).
    if (j == 0 || j == NTILE - 1) {
      asm volatile("s_waitcnt vmcnt(16)" ::: "memory");
    } else {
      asm volatile("s_waitcnt vmcnt(31)" ::: "memory");
    }
    __builtin_amdgcn_sched_barrier(0);  // keep ds_reads below the wait

    // compute tile j
    float xv[WIN];
#pragma unroll
    for (int i = 0; i < WIN; ++i) {
      const int t = tstart - HALO + i;
      xv[i] = ring[(t + 2048) & (RING - 1)][lane];
    }
    float* op = out + ((size_t)tstart * B_SZ + b) * C_SZ + c0 + lane;
#pragma unroll
    for (int o = 0; o < TT; ++o) {
      float a = 0.f;
#pragma unroll
      for (int k = 0; k < KW; ++k) a = fmaf(wk[k], xv[o + k], a);
      op[(size_t)o * ROWSTRIDE] = a;
    }
  }
}

extern "C" void kernel_launch(void* const* d_in, const int* in_sizes, int n_in,
                              void* d_out, int out_size, void* d_ws, size_t ws_size,
                              hipStream_t stream) {
  const float* x = (const float*)d_in[0];      // (T,B,C) f32
  const float* w = (const float*)d_in[1];      // (H,K) f32
  float* out = (float*)d_out;                  // (T,B,C) f32
  (void)in_sizes; (void)n_in; (void)out_size; (void)d_ws; (void)ws_size;

  dim3 grid((C_SZ / 64) * (T_LEN / CHUNK), B_SZ);  // (256, 8) = 2048 waves
  dim3 block(64);
  lightconv_kernel<<<grid, block, 0, stream>>>(x, w, out);
}

// Round 8
// 30.803 us; speedup vs baseline: 3.4972x; 1.0870x over previous
//
#include <hip/hip_runtime.h>
#include <math.h>

// LightconvLayer: x (T,B,C) f32, weight (H,K) f32 -> out (T,B,C) f32
// out[t,b,c] = sum_k softmax(weight[c/64])[k] * x[t+k-30, b, c] (zero-pad left)
//
// R8: wave-autonomous ring + prefetch-ahead-2 + width-16 global_load_lds +
//     compile-time ring slots (tb % 64 == 0 -> slot = (8*jj + i + 34) & 63).
//  - 1 wave owns (batch b, head = 64 ch, 128-row chunk); 16 tiles of TT=8.
//  - LDS ring 64 rows x 64 ch x f32 = 16 KB (reads 38 + in-flight writes 16
//    + 2 stale span 56 <= 64 rows).
//  - per tile: 2x global_load_lds(16B) stage tile j+2 (4 rows/instr:
//    lane l -> row +l/16, ch (l&15)), counted vmcnt (in-order retirement:
//    steady = S(j-2)+L(j+1)+S(j-1)+L(j+2) = 20), 38 imm-offset ds_reads,
//    248 FMA with SGPR taps, 8 dword stores. No s_barrier anywhere.
#define T_LEN 2048
#define B_SZ  8
#define C_SZ  1024
#define NH    16
#define KW    31
#define HALO  (KW - 1)        // 30
#define TT    8               // rows per tile
#define CHUNK 128             // rows per wave (multiple of RING -> tb%64==0)
#define NTILE (CHUNK / TT)    // 16
#define RING  64
#define WIN   (TT + HALO)     // 38
#define ROWSTRIDE (B_SZ * C_SZ)  // 8192 floats between t rows

#define GLOBAL_AS(p) ((const __attribute__((address_space(1))) void*)(p))
#define LDS_AS(p)    ((__attribute__((address_space(3))) void*)(p))

__global__ __launch_bounds__(64, 2) void lightconv_kernel(
    const float* __restrict__ x, const float* __restrict__ weight,
    float* __restrict__ out) {
  __shared__ float ring[RING][64];   // 16 KB, wave-private (1 wave/block)
  const int lane = threadIdx.x;

  const int cgrp = blockIdx.x & 15;  // head (C/64 = 16 = NH)
  const int tc   = blockIdx.x >> 4;  // t-chunk 0..15
  const int b    = blockIdx.y;
  const int c0   = cgrp * 64;
  const int tb   = tc * CHUNK;       // tb % 64 == 0

  // --- taps: uniform loads -> uniform softmax -> SGPR via readfirstlane ---
  float wv[KW];
  float m = -1e30f;
#pragma unroll
  for (int k = 0; k < KW; ++k) {
    wv[k] = weight[cgrp * KW + k];
    m = fmaxf(m, wv[k]);
  }
  float s = 0.f;
#pragma unroll
  for (int k = 0; k < KW; ++k) {
    wv[k] = expf(wv[k] - m);
    s += wv[k];
  }
  const float inv = 1.f / s;
  float wk[KW];
#pragma unroll
  for (int k = 0; k < KW; ++k) {
    wk[k] = __uint_as_float(
        __builtin_amdgcn_readfirstlane(__float_as_uint(wv[k] * inv)));
  }

  // per-lane offset for width-16 staging: lane l -> row l>>4, ch (l&15)*4B
  const float* xbase = x + (size_t)b * C_SZ + c0;
  const int lane_off = (lane >> 4) * ROWSTRIDE + (lane & 15) * 4;  // floats

  // --- prologue ---
  if (tb == 0) {
    // zero "rows -32..-1" = slots 32..63; load rows 0..7 -> slots 0..7
#pragma unroll
    for (int i = 0; i < 32; ++i) ring[32 + i][lane] = 0.f;
#pragma unroll
    for (int r4 = 0; r4 < 2; ++r4) {
      const float* gp = xbase + (size_t)(r4 * 4) * ROWSTRIDE + lane_off;
      __builtin_amdgcn_global_load_lds(GLOBAL_AS(gp),
                                       LDS_AS(&ring[r4 * 4][0]), 16, 0, 0);
    }
  } else {
    // rows tb-32 .. tb+7 (10 x 4-row loads) -> slots (32+4*r4)&63
#pragma unroll
    for (int r4 = 0; r4 < 10; ++r4) {
      const float* gp = xbase + (size_t)(tb - 32 + r4 * 4) * ROWSTRIDE + lane_off;
      __builtin_amdgcn_global_load_lds(GLOBAL_AS(gp),
                                       LDS_AS(&ring[(32 + 4 * r4) & (RING - 1)][0]),
                                       16, 0, 0);
    }
  }
  // stage tile 1 (rows tb+8..15 -> slots 8..15)
#pragma unroll
  for (int r4 = 0; r4 < 2; ++r4) {
    const float* gp = xbase + (size_t)(tb + TT + r4 * 4) * ROWSTRIDE + lane_off;
    __builtin_amdgcn_global_load_lds(GLOBAL_AS(gp),
                                     LDS_AS(&ring[8 + r4 * 4][0]), 16, 0, 0);
  }

  // --- main loop: 16 tiles, unroll 8 (slot period 8*TT = RING) ---
#pragma unroll 1
  for (int jo = 0; jo < 2; ++jo) {
#pragma unroll
    for (int jj = 0; jj < NTILE / 2; ++jj) {
      const int j = jo * 8 + jj;          // tile index (jj compile-time)
      const int tstart = tb + jo * 64 + jj * TT;

      // issue L(j+2): rows tstart+16..23 -> slots (8*jj+16..23)&63 (ct)
      if (j <= NTILE - 3) {
#pragma unroll
        for (int r4 = 0; r4 < 2; ++r4) {
          const float* gp =
              xbase + (size_t)(tstart + 2 * TT + r4 * 4) * ROWSTRIDE + lane_off;
          __builtin_amdgcn_global_load_lds(
              GLOBAL_AS(gp),
              LDS_AS(&ring[(8 * jj + 16 + r4 * 4) & (RING - 1)][0]), 16, 0, 0);
        }
      }
      // counted wait (in-order vmcnt): guarantee L(j) retired, keep rest in flight
      if (j == 0)                asm volatile("s_waitcnt vmcnt(4)"  ::: "memory");
      else if (j == 1)           asm volatile("s_waitcnt vmcnt(12)" ::: "memory");
      else if (j == NTILE - 2)   asm volatile("s_waitcnt vmcnt(18)" ::: "memory");
      else if (j == NTILE - 1)   asm volatile("s_waitcnt vmcnt(16)" ::: "memory");
      else                       asm volatile("s_waitcnt vmcnt(20)" ::: "memory");
      __builtin_amdgcn_sched_barrier(0);  // rule #18: pin ds_reads below

      // compute tile j: slots are compile-time -> imm-offset ds_reads
      float xv[WIN];
#pragma unroll
      for (int i = 0; i < WIN; ++i) {
        xv[i] = ring[(8 * jj + i + 34) & (RING - 1)][lane];
      }
      float* op = out + ((size_t)tstart * B_SZ + b) * C_SZ + c0 + lane;
#pragma unroll
      for (int o = 0; o < TT; ++o) {
        float a = 0.f;
#pragma unroll
        for (int k = 0; k < KW; ++k) a = fmaf(wk[k], xv[o + k], a);
        op[(size_t)o * ROWSTRIDE] = a;
      }
    }
  }
}

extern "C" void kernel_launch(void* const* d_in, const int* in_sizes, int n_in,
                              void* d_out, int out_size, void* d_ws, size_t ws_size,
                              hipStream_t stream) {
  const float* x = (const float*)d_in[0];      // (T,B,C) f32
  const float* w = (const float*)d_in[1];      // (H,K) f32
  float* out = (float*)d_out;                  // (T,B,C) f32
  (void)in_sizes; (void)n_in; (void)out_size; (void)d_ws; (void)ws_size;

  dim3 grid((C_SZ / 64) * (T_LEN / CHUNK), B_SZ);  // (256, 8) = 2048 waves
  dim3 block(64);
  lightconv_kernel<<<grid, block, 0, stream>>>(x, w, out);
}